// Round 4
// baseline (708.572 us; speedup 1.0000x reference)
//
#include <hip/hip_runtime.h>

typedef __bf16 bf16;
typedef __attribute__((ext_vector_type(8))) __bf16 bf16x8;
typedef __attribute__((ext_vector_type(4))) float f32x4;

constexpr int Bb = 4, S = 2048, Dd = 2048, H = 16, G = 4, HD = 128;
constexpr float L2E = 1.4426950408889634f;

__device__ inline f32x4 mfma16(bf16x8 a, bf16x8 b, f32x4 c) {
  return __builtin_amdgcn_mfma_f32_16x16x32_bf16(a, b, c, 0, 0, 0);
}

__device__ inline void gl_lds16(const void* g, void* l) {
  __builtin_amdgcn_global_load_lds(
      (const __attribute__((address_space(1))) void*)g,
      (__attribute__((address_space(3))) void*)l, 16, 0, 0);
}

// ---------------- fp32 -> bf16 elementwise (vectorized) ----------------
__global__ __launch_bounds__(256) void k_f32_to_bf16(
    const float* __restrict__ in, bf16* __restrict__ out, int n8) {
  int i = blockIdx.x * 256 + threadIdx.x;
  if (i >= n8) return;
  const float4* p = (const float4*)(in + (long long)i * 8);
  float4 a = p[0], b = p[1];
  bf16x8 v;
  v[0] = (bf16)a.x; v[1] = (bf16)a.y; v[2] = (bf16)a.z; v[3] = (bf16)a.w;
  v[4] = (bf16)b.x; v[5] = (bf16)b.y; v[6] = (bf16)b.z; v[7] = (bf16)b.w;
  *(bf16x8*)(out + (long long)i * 8) = v;
}

// ---------------- transpose + convert to bf16 ----------------
template <typename InT>
__global__ __launch_bounds__(256) void k_transpose_bf16(
    const InT* __restrict__ in, long long s1, int nb2, long long s2, int ldin,
    bf16* __restrict__ out, long long obatch, int ldout, int R, int C) {
  __shared__ float tile[32][33];
  int z = blockIdx.z;
  const InT* ip = in + (long long)(z / nb2) * s1 + (long long)(z % nb2) * s2;
  bf16* op = out + (long long)z * obatch;
  int c0 = blockIdx.x * 32, r0 = blockIdx.y * 32;
  int tx = threadIdx.x, ty = threadIdx.y;
#pragma unroll
  for (int i = 0; i < 4; ++i) {
    int r = r0 + ty + i * 8, c = c0 + tx;
    tile[ty + i * 8][tx] = (r < R && c < C) ? (float)ip[(long long)r * ldin + c] : 0.f;
  }
  __syncthreads();
#pragma unroll
  for (int i = 0; i < 4; ++i) {
    int c = c0 + ty + i * 8, r = r0 + tx;
    if (c < C && r < R) op[(long long)c * ldout + r] = (bf16)tile[tx][ty + i * 8];
  }
}

// ---------------- 256x256 software-pipelined bf16 GEMM ---------------------
// C = A(MxK) * Bt(NxK)^T. 512 thr = 8 waves (2Mx4N), BK=64, dbuf 128 KiB LDS,
// row-XOR swizzle via pre-swizzled global source. 4 phases/K-tile, each:
// [issue next phase's ds_reads][stage 1 unit][16 MFMA][vmcnt(4)][barrier].
// Ledger: every gl_lds has >=3 phases before its dependent ds_read.
template <typename CT>
__global__ __launch_bounds__(512, 2) void k_gemm256(
    const bf16* __restrict__ A, int lda, const bf16* __restrict__ Bt, int ldb,
    CT* __restrict__ C, int ldc, int M, int N, int K) {
  __shared__ bf16 ldsbuf[65536];  // 128 KB: [buf:64KB][A:32KB | B:32KB]
  char* lds2 = (char*)ldsbuf;
  const int tid = threadIdx.x;
  const int w = tid >> 6, lane = tid & 63;
  const int l16 = lane & 15, lh = lane >> 4;
  const int wr = w >> 2, wc = w & 3;
  const int nbn = N >> 8;
  const int cpx = gridDim.x >> 3;
  const int swz = (blockIdx.x & 7) * cpx + (blockIdx.x >> 3);
  const int bm = swz / nbn, bn = swz % nbn;
  const int m0 = bm << 8, n0 = bn << 8;

  const int lrow = lane >> 3;
  const int lcol = ((lane & 7) ^ lrow) * 8;  // pre-swizzled source column
  const int arb = wr * 128 + wc * 16;
  const int xg = wc >> 1, sg = wr * 2 + (wc & 1);
  const int brb = xg * 128 + (sg >> 1) * 64 + (sg & 1) * 16;
  const bf16* aS0 = A + (long long)(m0 + arb + lrow) * lda + lcol;
  const bf16* aS1 = A + (long long)(m0 + arb + 8 + lrow) * lda + lcol;
  const bf16* bS0 = Bt + (long long)(n0 + brb + lrow) * ldb + lcol;
  const bf16* bS1 = Bt + (long long)(n0 + brb + 8 + lrow) * ldb + lcol;

  // one "unit" = 16KB = 2 gl_lds/thread; guarded against K overrun
  auto stageA = [&](int buf, int k0, int hi) {
    if (k0 >= K) return;
    gl_lds16(aS0 + (long long)hi * 64 * lda + k0,
             lds2 + buf * 65536 + (arb + hi * 64) * 128);
    gl_lds16(aS1 + (long long)hi * 64 * lda + k0,
             lds2 + buf * 65536 + (arb + hi * 64 + 8) * 128);
  };
  auto stageB = [&](int buf, int k0, int hi) {
    if (k0 >= K) return;
    gl_lds16(bS0 + (long long)hi * 32 * ldb + k0,
             lds2 + buf * 65536 + 32768 + (brb + hi * 32) * 128);
    gl_lds16(bS1 + (long long)hi * 32 * ldb + k0,
             lds2 + buf * 65536 + 32768 + (brb + hi * 32 + 8) * 128);
  };

  const int swzc = (l16 & 7) << 4;
  auto rdA = [&](bf16x8 (&dst)[4][2], const char* L, int mh) {
#pragma unroll
    for (int m = 0; m < 4; ++m)
#pragma unroll
      for (int ks = 0; ks < 2; ++ks)
        dst[m][ks] = *(const bf16x8*)(L + (wr * 128 + mh * 64 + m * 16 + l16) * 128 +
                                      ((ks * 64 + lh * 16) ^ swzc));
  };
  auto rdB = [&](bf16x8 (&dst)[2][2], const char* L, int nh) {
#pragma unroll
    for (int n = 0; n < 2; ++n)
#pragma unroll
      for (int ks = 0; ks < 2; ++ks)
        dst[n][ks] = *(const bf16x8*)(L + 32768 + (wc * 64 + nh * 32 + n * 16 + l16) * 128 +
                                      ((ks * 64 + lh * 16) ^ swzc));
  };

  f32x4 acc[8][4] = {};
  bf16x8 aflo[4][2], afhi[4][2], bn0[2][2], bn1[2][2], bn0b[2][2];
  const int NT = K >> 6;

  // prologue: SA0(0),SB0(0),SB1(0),SA1(0)->buf0; SA0(1)->buf1
  stageA(0, 0, 0);
  stageB(0, 0, 0);
  stageB(0, 0, 1);
  stageA(0, 0, 1);
  stageA(1, 64, 0);
  asm volatile("s_waitcnt vmcnt(4)" ::: "memory");  // SA0,SB0,SB1(0) resident
  __builtin_amdgcn_s_barrier();
  rdA(aflo, lds2, 0);
  rdB(bn0, lds2, 0);

  for (int t = 0; t < NT; ++t) {
    const int buf = t & 1;
    const char* L = lds2 + buf * 65536;
    const char* Ln = lds2 + (buf ^ 1) * 65536;
    const int k1 = (t + 1) << 6;
    // ---- P1: MFMA (mlo x n01); reads bn1; stage SB0(t+1) ----
    rdB(bn1, L, 1);
    stageB(buf ^ 1, k1, 0);
    __builtin_amdgcn_sched_barrier(0);
    __builtin_amdgcn_s_setprio(1);
#pragma unroll
    for (int m = 0; m < 4; ++m)
#pragma unroll
      for (int n = 0; n < 2; ++n)
#pragma unroll
        for (int ks = 0; ks < 2; ++ks)
          acc[m][n] = mfma16(aflo[m][ks], bn0[n][ks], acc[m][n]);
    __builtin_amdgcn_s_setprio(0);
    asm volatile("s_waitcnt vmcnt(4)" ::: "memory");
    __builtin_amdgcn_s_barrier();
    // ---- P2: MFMA (mlo x n23); reads afhi; stage SB1(t+1) ----
    rdA(afhi, L, 1);
    stageB(buf ^ 1, k1, 1);
    __builtin_amdgcn_sched_barrier(0);
    __builtin_amdgcn_s_setprio(1);
#pragma unroll
    for (int m = 0; m < 4; ++m)
#pragma unroll
      for (int n = 0; n < 2; ++n)
#pragma unroll
        for (int ks = 0; ks < 2; ++ks)
          acc[m][2 + n] = mfma16(aflo[m][ks], bn1[n][ks], acc[m][2 + n]);
    __builtin_amdgcn_s_setprio(0);
    asm volatile("s_waitcnt vmcnt(4)" ::: "memory");
    __builtin_amdgcn_s_barrier();
    // ---- P3: MFMA (mhi x n23); re-reads bn0; stage SA1(t+1) ----
    rdB(bn0b, L, 0);
    stageA(buf ^ 1, k1, 1);
    __builtin_amdgcn_sched_barrier(0);
    __builtin_amdgcn_s_setprio(1);
#pragma unroll
    for (int m = 0; m < 4; ++m)
#pragma unroll
      for (int n = 0; n < 2; ++n)
#pragma unroll
        for (int ks = 0; ks < 2; ++ks)
          acc[4 + m][2 + n] = mfma16(afhi[m][ks], bn1[n][ks], acc[4 + m][2 + n]);
    __builtin_amdgcn_s_setprio(0);
    asm volatile("s_waitcnt vmcnt(4)" ::: "memory");
    __builtin_amdgcn_s_barrier();
    // ---- P4: MFMA (mhi x n01); reads next aflo/bn0; stage SA0(t+2) ----
    if (t + 1 < NT) {
      rdA(aflo, Ln, 0);
      rdB(bn0, Ln, 0);
    }
    stageA(buf, (t + 2) << 6, 0);
    __builtin_amdgcn_sched_barrier(0);
    __builtin_amdgcn_s_setprio(1);
#pragma unroll
    for (int m = 0; m < 4; ++m)
#pragma unroll
      for (int n = 0; n < 2; ++n)
#pragma unroll
        for (int ks = 0; ks < 2; ++ks)
          acc[4 + m][n] = mfma16(afhi[m][ks], bn0b[n][ks], acc[4 + m][n]);
    __builtin_amdgcn_s_setprio(0);
    asm volatile("s_waitcnt vmcnt(4)" ::: "memory");
    __builtin_amdgcn_s_barrier();
  }

#pragma unroll
  for (int m = 0; m < 8; ++m)
#pragma unroll
    for (int n = 0; n < 4; ++n)
#pragma unroll
      for (int r = 0; r < 4; ++r)
        C[(long long)(m0 + wr * 128 + m * 16 + lh * 4 + r) * ldc + n0 + wc * 64 +
          n * 16 + l16] = (CT)acc[m][n][r];
}

// ---------------- RMSNorm + RoPE (wave per (b,s,h) row) ----------------
__global__ __launch_bounds__(256) void k_rms_rope(
    const bf16* __restrict__ in, int ldin, int nh, const float* __restrict__ scale,
    const float* __restrict__ cosT, const float* __restrict__ sinT,
    bf16* __restrict__ out, float oscale, int nwaves) {
  int wid = (blockIdx.x * 256 + threadIdx.x) >> 6;
  if (wid >= nwaves) return;
  int lane = threadIdx.x & 63;
  int h = wid % nh;
  int bs = wid / nh;
  int s = bs % S;
  int b = bs / S;
  const bf16* ip = in + (long long)bs * ldin + h * HD;
  float x1 = (float)ip[lane], x2 = (float)ip[lane + 64];
  float ss = x1 * x1 + x2 * x2;
#pragma unroll
  for (int m = 1; m < 64; m <<= 1) ss += __shfl_xor(ss, m);
  float rms = rsqrtf(ss * (1.f / 128.f) + 1e-6f);
  float n1 = x1 * rms * (1.f + scale[lane]);
  float n2 = x2 * rms * (1.f + scale[lane + 64]);
  float o1 = (n1 * cosT[s * 128 + lane] - n2 * sinT[s * 128 + lane]) * oscale;
  float o2 = (n2 * cosT[s * 128 + lane + 64] + n1 * sinT[s * 128 + lane + 64]) * oscale;
  bf16* op = out + (((long long)b * nh + h) * S + s) * HD;
  op[lane] = (bf16)o1;
  op[lane + 64] = (bf16)o2;
}

// ---------------- sigmoid in-place on strided bf16 slice ----------------
__global__ __launch_bounds__(256) void k_sigmoid(bf16* __restrict__ p, int ld,
                                                 int cols8, int n) {
  int i = blockIdx.x * 256 + threadIdx.x;
  if (i >= n) return;
  int row = i / cols8, c = (i % cols8) * 8;
  bf16x8* q = (bf16x8*)(p + (long long)row * ld + c);
  bf16x8 v = *q;
#pragma unroll
  for (int j = 0; j < 8; ++j) {
    float f = (float)v[j];
    v[j] = (bf16)(1.f / (1.f + exp2f(-f * L2E)));
  }
  *q = v;
}

// ---------------- causal GQA flash attention v2 ----------------
__global__ __launch_bounds__(512, 2) void k_flash2(
    const bf16* __restrict__ Q, const bf16* __restrict__ Kb,
    const bf16* __restrict__ Vt, const bf16* __restrict__ gate, int ldg,
    bf16* __restrict__ outc, int ldo) {
  __shared__ bf16 Ks[2][64 * 128];   // [kv][d], swizzled: byte ^= (kv&7)<<4
  __shared__ bf16 Vs[2][128 * 64];   // [d][kv], swizzled: byte ^= (d&7)<<4
  __shared__ bf16 Ps[8][32 * 72];
  const int tid = threadIdx.x, w = tid >> 6, lane = tid & 63;
  const int l16 = lane & 15, lh = lane >> 4;
  const int bh = blockIdx.x & 63;
  const int qi = blockIdx.x >> 6;
  const int qc = 7 - qi;
  const int h = bh & 15, b = bh >> 4, g = h >> 2;
  const int qbase = qc * 256;
  const int q0w = qbase + w * 32;
  const bf16* qp = Q + (((long long)b * H + h) * S + q0w) * HD;
  const bf16* kp = Kb + ((long long)b * G + g) * S * HD;
  const bf16* vp = Vt + ((long long)b * G + g) * (long long)HD * S;

  bf16x8 aq[2][4];
#pragma unroll
  for (int m = 0; m < 2; ++m)
#pragma unroll
    for (int ks = 0; ks < 4; ++ks)
      aq[m][ks] = *(const bf16x8*)(qp + (long long)(m * 16 + l16) * HD + ks * 32 + lh * 8);

  f32x4 acc[2][8] = {};
  float mrow[2][4], lrow[2][4];
#pragma unroll
  for (int m = 0; m < 2; ++m)
#pragma unroll
    for (int r = 0; r < 4; ++r) { mrow[m][r] = -1e30f; lrow[m][r] = 0.f; }

  const int ntiles = qc * 4 + 4;

  auto stage = [&](int bi, int t) {
    const int kv0 = t << 6;
#pragma unroll
    for (int i = 0; i < 2; ++i) {
      int c = w * 128 + i * 64 + lane;
      int row = c >> 4;
      int cb = ((c & 15) << 4) ^ ((row & 7) << 4);
      gl_lds16(kp + (long long)(kv0 + row) * HD + (cb >> 1),
               (char*)Ks[bi] + (w * 128 + i * 64) * 16);
      int rowv = c >> 3;
      int cbv = ((c & 7) << 4) ^ ((rowv & 7) << 4);
      gl_lds16(vp + (long long)rowv * S + kv0 + (cbv >> 1),
               (char*)Vs[bi] + (w * 128 + i * 64) * 16);
    }
  };

  stage(0, 0);
  __syncthreads();

  for (int t = 0; t < ntiles; ++t) {
    const int buf = t & 1;
    if (t + 1 < ntiles) stage(buf ^ 1, t + 1);
    const int kv0 = t << 6;
    if (kv0 <= q0w + 31) {
      f32x4 s[2][4] = {};
#pragma unroll
      for (int ks = 0; ks < 4; ++ks)
#pragma unroll
        for (int n = 0; n < 4; ++n) {
          int row = n * 16 + l16;
          int off = row * 256 + ((ks * 64 + lh * 16) ^ ((row & 7) << 4));
          bf16x8 kb = *(const bf16x8*)((const char*)Ks[buf] + off);
#pragma unroll
          for (int m = 0; m < 2; ++m) s[m][n] = mfma16(aq[m][ks], kb, s[m][n]);
        }
      if (kv0 + 63 > q0w) {
#pragma unroll
        for (int m = 0; m < 2; ++m)
#pragma unroll
          for (int n = 0; n < 4; ++n)
#pragma unroll
            for (int r = 0; r < 4; ++r) {
              int col = kv0 + n * 16 + l16;
              int rowg = q0w + m * 16 + lh * 4 + r;
              if (col > rowg) s[m][n][r] = -1e30f;
            }
      }
      float pm[2][4];
#pragma unroll
      for (int m = 0; m < 2; ++m)
#pragma unroll
        for (int r = 0; r < 4; ++r)
          pm[m][r] = fmaxf(fmaxf(s[m][0][r], s[m][1][r]), fmaxf(s[m][2][r], s[m][3][r]));
#pragma unroll
      for (int st = 1; st < 16; st <<= 1)
#pragma unroll
        for (int m = 0; m < 2; ++m)
#pragma unroll
          for (int r = 0; r < 4; ++r) pm[m][r] = fmaxf(pm[m][r], __shfl_xor(pm[m][r], st));
      float resc[2][4];
#pragma unroll
      for (int m = 0; m < 2; ++m)
#pragma unroll
        for (int r = 0; r < 4; ++r) {
          float mn = fmaxf(mrow[m][r], pm[m][r]);
          resc[m][r] = exp2f(mrow[m][r] - mn);
          mrow[m][r] = mn;
        }
#pragma unroll
      for (int m = 0; m < 2; ++m)
#pragma unroll
        for (int n = 0; n < 4; ++n) {
#pragma unroll
          for (int r = 0; r < 4; ++r) {
            float p = exp2f(s[m][n][r] - mrow[m][r]);
            s[m][n][r] = p;
            Ps[w][(m * 16 + lh * 4 + r) * 72 + n * 16 + l16] = (bf16)p;
          }
        }
#pragma unroll
      for (int m = 0; m < 2; ++m)
#pragma unroll
        for (int r = 0; r < 4; ++r)
          lrow[m][r] = lrow[m][r] * resc[m][r] +
                       (s[m][0][r] + s[m][1][r] + s[m][2][r] + s[m][3][r]);
#pragma unroll
      for (int m = 0; m < 2; ++m)
#pragma unroll
        for (int dt = 0; dt < 8; ++dt)
#pragma unroll
          for (int r = 0; r < 4; ++r) acc[m][dt][r] *= resc[m][r];
      bf16x8 pa[2][2];
#pragma unroll
      for (int m = 0; m < 2; ++m)
#pragma unroll
        for (int kf = 0; kf < 2; ++kf)
          pa[m][kf] = *(const bf16x8*)((const char*)&Ps[w][0] +
                                       (m * 16 + l16) * 144 + kf * 64 + lh * 16);
#pragma unroll
      for (int dt = 0; dt < 8; ++dt) {
        int d = dt * 16 + l16;
#pragma unroll
        for (int kf = 0; kf < 2; ++kf) {
          int off = d * 128 + ((kf * 64 + lh * 16) ^ ((d & 7) << 4));
          bf16x8 vb = *(const bf16x8*)((const char*)Vs[buf] + off);
#pragma unroll
          for (int m = 0; m < 2; ++m) acc[m][dt] = mfma16(pa[m][kf], vb, acc[m][dt]);
        }
      }
    }
    __syncthreads();
  }

#pragma unroll
  for (int st = 1; st < 16; st <<= 1)
#pragma unroll
    for (int m = 0; m < 2; ++m)
#pragma unroll
      for (int r = 0; r < 4; ++r) lrow[m][r] += __shfl_xor(lrow[m][r], st);
  float inv[2][4];
#pragma unroll
  for (int m = 0; m < 2; ++m)
#pragma unroll
    for (int r = 0; r < 4; ++r) inv[m][r] = 1.f / lrow[m][r];
#pragma unroll
  for (int m = 0; m < 2; ++m)
#pragma unroll
    for (int dt = 0; dt < 8; ++dt)
#pragma unroll
      for (int r = 0; r < 4; ++r) {
        int rowg = q0w + m * 16 + lh * 4 + r;
        long long row = (long long)b * S + rowg;
        int col = h * HD + dt * 16 + l16;
        float gv = (float)gate[row * ldg + col];
        outc[row * ldo + col] = (bf16)(acc[m][dt][r] * inv[m][r] * gv);
      }
}

extern "C" void kernel_launch(void* const* d_in, const int* in_sizes, int n_in,
                              void* d_out, int out_size, void* d_ws, size_t ws_size,
                              hipStream_t stream) {
  const float* x = (const float*)d_in[0];
  const float* cosT = (const float*)d_in[2];
  const float* sinT = (const float*)d_in[3];
  const float* wq = (const float*)d_in[4];
  const float* wk = (const float*)d_in[5];
  const float* wv = (const float*)d_in[6];
  const float* wg = (const float*)d_in[7];
  const float* wo = (const float*)d_in[8];
  const float* qs = (const float*)d_in[9];
  const float* ksc = (const float*)d_in[10];
  float* out = (float*)d_out;
  char* ws = (char*)d_ws;

  if (ws_size < 146800640) return;
  bf16* xb = (bf16*)(ws);
  bf16* wcat = (bf16*)(ws + 33554432);
  bf16* woT = (bf16*)(ws + 54525952);
  bf16* C1 = (bf16*)(ws + 62914560);
  bf16* qbuf = xb;
  bf16* kbuf = wcat;
  bf16* vtbuf = wcat + 4194304;
  bf16* gatep = C1 + 3072;
  bf16* ctxg = C1;

  dim3 tb(32, 8);
  k_f32_to_bf16<<<8192, 256, 0, stream>>>(x, xb, Bb * S * Dd / 8);
  k_transpose_bf16<float><<<dim3(64, 64, 1), tb, 0, stream>>>(
      wq, 0, 1, 0, 2048, wcat, 0, 2048, 2048, 2048);
  k_transpose_bf16<float><<<dim3(16, 64, 1), tb, 0, stream>>>(
      wk, 0, 1, 0, 512, wcat + 2048 * 2048, 0, 2048, 2048, 512);
  k_transpose_bf16<float><<<dim3(16, 64, 1), tb, 0, stream>>>(
      wv, 0, 1, 0, 512, wcat + 2560 * 2048, 0, 2048, 2048, 512);
  k_transpose_bf16<float><<<dim3(64, 64, 1), tb, 0, stream>>>(
      wg, 0, 1, 0, 2048, wcat + 3072 * 2048, 0, 2048, 2048, 2048);
  k_transpose_bf16<float><<<dim3(64, 64, 1), tb, 0, stream>>>(
      wo, 0, 1, 0, 2048, woT, 0, 2048, 2048, 2048);
  // fused QKVG GEMM: (8192x2048) @ (2048x5120) -> C1 bf16
  k_gemm256<bf16><<<32 * 20, 512, 0, stream>>>(xb, 2048, wcat, 2048, C1, 5120,
                                               8192, 5120, 2048);
  // RMSNorm + RoPE; L2E/sqrt(128) folded into q so attention uses exp2
  k_rms_rope<<<32768, 256, 0, stream>>>(C1, 5120, 16, qs, cosT, sinT, qbuf,
                                        0.12751879523209308f, 131072);
  k_rms_rope<<<8192, 256, 0, stream>>>(C1 + 2048, 5120, 4, ksc, cosT, sinT, kbuf,
                                       1.0f, 32768);
  // V -> V^T (B,G,128,S)
  k_transpose_bf16<bf16><<<dim3(4, 64, 16), tb, 0, stream>>>(
      C1 + 2560, (long long)2048 * 5120, 4, 128, 5120, vtbuf,
      (long long)128 * 2048, 2048, 2048, 128);
  // gate = sigmoid(xwg) in-place
  k_sigmoid<<<8192, 256, 0, stream>>>(gatep, 5120, 256, 2097152);
  // flash attention v2 + gate -> C1 cols 0:2048
  k_flash2<<<512, 512, 0, stream>>>(qbuf, kbuf, vtbuf, gatep, 5120, ctxg, 5120);
  // output GEMM: (8192x2048) @ (2048x2048) -> out fp32
  k_gemm256<float><<<32 * 8, 512, 0, stream>>>(ctxg, 5120, woT, 2048, out, 2048,
                                               8192, 2048, 2048);
}

// Round 5
// 478.944 us; speedup vs baseline: 1.4794x; 1.4794x over previous
//
#include <hip/hip_runtime.h>

typedef __bf16 bf16;
typedef __attribute__((ext_vector_type(8))) __bf16 bf16x8;
typedef __attribute__((ext_vector_type(4))) float f32x4;

constexpr int Bb = 4, S = 2048, Dd = 2048, H = 16, G = 4, HD = 128;
constexpr float L2E = 1.4426950408889634f;

__device__ inline f32x4 mfma16(bf16x8 a, bf16x8 b, f32x4 c) {
  return __builtin_amdgcn_mfma_f32_16x16x32_bf16(a, b, c, 0, 0, 0);
}

__device__ inline void gl_lds16(const void* g, void* l) {
  __builtin_amdgcn_global_load_lds(
      (const __attribute__((address_space(1))) void*)g,
      (__attribute__((address_space(3))) void*)l, 16, 0, 0);
}

// ---------------- fp32 -> bf16 elementwise (vectorized) ----------------
__global__ __launch_bounds__(256) void k_f32_to_bf16(
    const float* __restrict__ in, bf16* __restrict__ out, int n8) {
  int i = blockIdx.x * 256 + threadIdx.x;
  if (i >= n8) return;
  const float4* p = (const float4*)(in + (long long)i * 8);
  float4 a = p[0], b = p[1];
  bf16x8 v;
  v[0] = (bf16)a.x; v[1] = (bf16)a.y; v[2] = (bf16)a.z; v[3] = (bf16)a.w;
  v[4] = (bf16)b.x; v[5] = (bf16)b.y; v[6] = (bf16)b.z; v[7] = (bf16)b.w;
  *(bf16x8*)(out + (long long)i * 8) = v;
}

// ---------------- transpose + convert to bf16 ----------------
template <typename InT>
__global__ __launch_bounds__(256) void k_transpose_bf16(
    const InT* __restrict__ in, long long s1, int nb2, long long s2, int ldin,
    bf16* __restrict__ out, long long obatch, int ldout, int R, int C) {
  __shared__ float tile[32][33];
  int z = blockIdx.z;
  const InT* ip = in + (long long)(z / nb2) * s1 + (long long)(z % nb2) * s2;
  bf16* op = out + (long long)z * obatch;
  int c0 = blockIdx.x * 32, r0 = blockIdx.y * 32;
  int tx = threadIdx.x, ty = threadIdx.y;
#pragma unroll
  for (int i = 0; i < 4; ++i) {
    int r = r0 + ty + i * 8, c = c0 + tx;
    tile[ty + i * 8][tx] = (r < R && c < C) ? (float)ip[(long long)r * ldin + c] : 0.f;
  }
  __syncthreads();
#pragma unroll
  for (int i = 0; i < 4; ++i) {
    int c = c0 + ty + i * 8, r = r0 + tx;
    if (c < C && r < R) op[(long long)c * ldout + r] = (bf16)tile[tx][ty + i * 8];
  }
}

// ---------------- 256x256 8-phase bf16 GEMM (R3 known-good) ----------------
template <typename CT>
__global__ __launch_bounds__(512, 2) void k_gemm256(
    const bf16* __restrict__ A, int lda, const bf16* __restrict__ Bt, int ldb,
    CT* __restrict__ C, int ldc, int M, int N, int K) {
  __shared__ bf16 ldsbuf[65536];  // 128 KB: [buf:64KB][A:32KB | B:32KB]
  char* lds2 = (char*)ldsbuf;
  const int tid = threadIdx.x;
  const int w = tid >> 6, lane = tid & 63;
  const int l16 = lane & 15, lh = lane >> 4;
  const int wr = w >> 2, wc = w & 3;
  const int nbn = N >> 8;
  const int cpx = gridDim.x >> 3;
  const int swz = (blockIdx.x & 7) * cpx + (blockIdx.x >> 3);
  const int bm = swz / nbn, bn = swz % nbn;
  const int m0 = bm << 8, n0 = bn << 8;

  const int lrow = lane >> 3;
  const int lcol = ((lane & 7) ^ lrow) * 8;
  const int arb = wr * 128 + wc * 16;
  const int xg = wc >> 1, sg = wr * 2 + (wc & 1);
  const int brb = xg * 128 + (sg >> 1) * 64 + (sg & 1) * 16;
  const bf16* aS0 = A + (long long)(m0 + arb + lrow) * lda + lcol;
  const bf16* aS1 = A + (long long)(m0 + arb + 8 + lrow) * lda + lcol;
  const bf16* bS0 = Bt + (long long)(n0 + brb + lrow) * ldb + lcol;
  const bf16* bS1 = Bt + (long long)(n0 + brb + 8 + lrow) * ldb + lcol;

  auto stageA = [&](int buf, int k0, int hi) {
    gl_lds16(aS0 + (long long)hi * 64 * lda + k0,
             lds2 + buf * 65536 + (arb + hi * 64) * 128);
    gl_lds16(aS1 + (long long)hi * 64 * lda + k0,
             lds2 + buf * 65536 + (arb + hi * 64 + 8) * 128);
  };
  auto stageB = [&](int buf, int k0, int hi) {
    gl_lds16(bS0 + (long long)hi * 32 * ldb + k0,
             lds2 + buf * 65536 + 32768 + (brb + hi * 32) * 128);
    gl_lds16(bS1 + (long long)hi * 32 * ldb + k0,
             lds2 + buf * 65536 + 32768 + (brb + hi * 32 + 8) * 128);
  };

  f32x4 acc[8][4] = {};
  const int NT = K >> 6;

  stageA(0, 0, 0);
  stageB(0, 0, 0);
  stageB(0, 0, 1);
  stageA(0, 0, 1);
  asm volatile("s_waitcnt vmcnt(4)" ::: "memory");
  __builtin_amdgcn_s_barrier();

  const int swzc = (l16 & 7) << 4;
  for (int t = 0; t < NT; ++t) {
    const int buf = t & 1, nb = buf ^ 1;
    const int kn = (t + 1) << 6;
    const bool more = (t + 1 < NT);
    const char* La = lds2 + buf * 65536;
    const char* Lb = La + 32768;
    bf16x8 af[4][2], bn0[2][2], bn1[2][2];
    // ======== phase 1: quadrant (m0-3, n0-1) ========
    if (more) stageA(nb, kn, 0);
#pragma unroll
    for (int m = 0; m < 4; ++m)
#pragma unroll
      for (int ks = 0; ks < 2; ++ks)
        af[m][ks] = *(const bf16x8*)(La + (wr * 128 + m * 16 + l16) * 128 +
                                     ((ks * 64 + lh * 16) ^ swzc));
#pragma unroll
    for (int n = 0; n < 2; ++n)
#pragma unroll
      for (int ks = 0; ks < 2; ++ks)
        bn0[n][ks] = *(const bf16x8*)(Lb + (wc * 64 + n * 16 + l16) * 128 +
                                      ((ks * 64 + lh * 16) ^ swzc));
    __builtin_amdgcn_s_barrier();
    asm volatile("s_waitcnt lgkmcnt(0)" ::: "memory");
    __builtin_amdgcn_sched_barrier(0);
    __builtin_amdgcn_s_setprio(1);
#pragma unroll
    for (int m = 0; m < 4; ++m)
#pragma unroll
      for (int n = 0; n < 2; ++n)
#pragma unroll
        for (int ks = 0; ks < 2; ++ks)
          acc[m][n] = mfma16(af[m][ks], bn0[n][ks], acc[m][n]);
    __builtin_amdgcn_s_setprio(0);
    asm volatile("s_waitcnt vmcnt(4)" ::: "memory");
    __builtin_amdgcn_s_barrier();
    // ======== phase 2: quadrant (m0-3, n2-3) ========
    if (more) stageB(nb, kn, 0);
#pragma unroll
    for (int n = 0; n < 2; ++n)
#pragma unroll
      for (int ks = 0; ks < 2; ++ks)
        bn1[n][ks] = *(const bf16x8*)(Lb + (wc * 64 + 32 + n * 16 + l16) * 128 +
                                      ((ks * 64 + lh * 16) ^ swzc));
    __builtin_amdgcn_s_barrier();
    asm volatile("s_waitcnt lgkmcnt(0)" ::: "memory");
    __builtin_amdgcn_sched_barrier(0);
    __builtin_amdgcn_s_setprio(1);
#pragma unroll
    for (int m = 0; m < 4; ++m)
#pragma unroll
      for (int n = 0; n < 2; ++n)
#pragma unroll
        for (int ks = 0; ks < 2; ++ks)
          acc[m][2 + n] = mfma16(af[m][ks], bn1[n][ks], acc[m][2 + n]);
    __builtin_amdgcn_s_setprio(0);
    asm volatile("s_waitcnt vmcnt(4)" ::: "memory");
    __builtin_amdgcn_s_barrier();
    // ======== phase 3: quadrant (m4-7, n2-3) ========
    if (more) stageB(nb, kn, 1);
#pragma unroll
    for (int m = 0; m < 4; ++m)
#pragma unroll
      for (int ks = 0; ks < 2; ++ks)
        af[m][ks] = *(const bf16x8*)(La + (wr * 128 + 64 + m * 16 + l16) * 128 +
                                     ((ks * 64 + lh * 16) ^ swzc));
    __builtin_amdgcn_s_barrier();
    asm volatile("s_waitcnt lgkmcnt(0)" ::: "memory");
    __builtin_amdgcn_sched_barrier(0);
    __builtin_amdgcn_s_setprio(1);
#pragma unroll
    for (int m = 0; m < 4; ++m)
#pragma unroll
      for (int n = 0; n < 2; ++n)
#pragma unroll
        for (int ks = 0; ks < 2; ++ks)
          acc[4 + m][2 + n] = mfma16(af[m][ks], bn1[n][ks], acc[4 + m][2 + n]);
    __builtin_amdgcn_s_setprio(0);
    __builtin_amdgcn_s_barrier();
    // ======== phase 4: quadrant (m4-7, n0-1), no new ds_reads ========
    if (more) stageA(nb, kn, 1);
    __builtin_amdgcn_s_barrier();
    __builtin_amdgcn_s_setprio(1);
#pragma unroll
    for (int m = 0; m < 4; ++m)
#pragma unroll
      for (int n = 0; n < 2; ++n)
#pragma unroll
        for (int ks = 0; ks < 2; ++ks)
          acc[4 + m][n] = mfma16(af[m][ks], bn0[n][ks], acc[4 + m][n]);
    __builtin_amdgcn_s_setprio(0);
    asm volatile("s_waitcnt vmcnt(4)" ::: "memory");
    __builtin_amdgcn_s_barrier();
  }

#pragma unroll
  for (int m = 0; m < 8; ++m)
#pragma unroll
    for (int n = 0; n < 4; ++n)
#pragma unroll
      for (int r = 0; r < 4; ++r)
        C[(long long)(m0 + wr * 128 + m * 16 + lh * 4 + r) * ldc + n0 + wc * 64 +
          n * 16 + l16] = (CT)acc[m][n][r];
}

// ---------------- RMSNorm + RoPE (wave per (b,s,h) row) ----------------
__global__ __launch_bounds__(256) void k_rms_rope(
    const bf16* __restrict__ in, int ldin, int nh, const float* __restrict__ scale,
    const float* __restrict__ cosT, const float* __restrict__ sinT,
    bf16* __restrict__ out, float oscale, int nwaves) {
  int wid = (blockIdx.x * 256 + threadIdx.x) >> 6;
  if (wid >= nwaves) return;
  int lane = threadIdx.x & 63;
  int h = wid % nh;
  int bs = wid / nh;
  int s = bs % S;
  int b = bs / S;
  const bf16* ip = in + (long long)bs * ldin + h * HD;
  float x1 = (float)ip[lane], x2 = (float)ip[lane + 64];
  float ss = x1 * x1 + x2 * x2;
#pragma unroll
  for (int m = 1; m < 64; m <<= 1) ss += __shfl_xor(ss, m);
  float rms = rsqrtf(ss * (1.f / 128.f) + 1e-6f);
  float n1 = x1 * rms * (1.f + scale[lane]);
  float n2 = x2 * rms * (1.f + scale[lane + 64]);
  float o1 = (n1 * cosT[s * 128 + lane] - n2 * sinT[s * 128 + lane]) * oscale;
  float o2 = (n2 * cosT[s * 128 + lane + 64] + n1 * sinT[s * 128 + lane + 64]) * oscale;
  bf16* op = out + (((long long)b * nh + h) * S + s) * HD;
  op[lane] = (bf16)o1;
  op[lane + 64] = (bf16)o2;
}

// ---------------- sigmoid in-place on strided bf16 slice ----------------
__global__ __launch_bounds__(256) void k_sigmoid(bf16* __restrict__ p, int ld,
                                                 int cols8, int n) {
  int i = blockIdx.x * 256 + threadIdx.x;
  if (i >= n) return;
  int row = i / cols8, c = (i % cols8) * 8;
  bf16x8* q = (bf16x8*)(p + (long long)row * ld + c);
  bf16x8 v = *q;
#pragma unroll
  for (int j = 0; j < 8; ++j) {
    float f = (float)v[j];
    v[j] = (bf16)(1.f / (1.f + exp2f(-f * L2E)));
  }
  *q = v;
}

// ---------------- causal GQA flash attention v3 ----------------
// 8 waves x 32 Q rows. K dbuf (32KB) + V single-buf (16KB) + swizzled Ps
// (32KB) = 80KB LDS -> 2 blocks/CU. Counted waits: vmcnt(2)+bar before PV,
// vmcnt(0)+bar at tile end. Defer-max (THR=8) skips reduce+rescale.
__global__ __launch_bounds__(512, 2) void k_flash3(
    const bf16* __restrict__ Q, const bf16* __restrict__ Kb,
    const bf16* __restrict__ Vt, const bf16* __restrict__ gate, int ldg,
    bf16* __restrict__ outc, int ldo) {
  __shared__ bf16 Ks[2][64 * 128];   // [kv][d], byte ^= (kv&7)<<4
  __shared__ bf16 Vs[128 * 64];      // [d][kv], byte ^= (d&7)<<4 (single buf)
  __shared__ bf16 Ps[8][32 * 64];    // per-wave P, byte ^= (row&7)<<4
  const int tid = threadIdx.x, w = tid >> 6, lane = tid & 63;
  const int l16 = lane & 15, lh = lane >> 4;
  const int bh = blockIdx.x & 63;
  const int qi = blockIdx.x >> 6;
  const int qc = 7 - qi;  // heavy chunks first
  const int h = bh & 15, b = bh >> 4, g = h >> 2;
  const int qbase = qc * 256;
  const int q0w = qbase + w * 32;
  const bf16* qp = Q + (((long long)b * H + h) * S + q0w) * HD;
  const bf16* kp = Kb + ((long long)b * G + g) * S * HD;
  const bf16* vp = Vt + ((long long)b * G + g) * (long long)HD * S;

  bf16x8 aq[2][4];
#pragma unroll
  for (int m = 0; m < 2; ++m)
#pragma unroll
    for (int ks = 0; ks < 4; ++ks)
      aq[m][ks] = *(const bf16x8*)(qp + (long long)(m * 16 + l16) * HD + ks * 32 + lh * 8);

  f32x4 acc[2][8] = {};
  float mrow[2][4], lrow[2][4];
#pragma unroll
  for (int m = 0; m < 2; ++m)
#pragma unroll
    for (int r = 0; r < 4; ++r) { mrow[m][r] = -1e30f; lrow[m][r] = 0.f; }

  const int ntiles = qc * 4 + 4;

  auto stageK = [&](int bi, int t) {
    const int kv0 = t << 6;
#pragma unroll
    for (int i = 0; i < 2; ++i) {
      int c = w * 128 + i * 64 + lane;  // 1024 16B-chunks
      int row = c >> 4;
      int cb = ((c & 15) << 4) ^ ((row & 7) << 4);
      gl_lds16(kp + (long long)(kv0 + row) * HD + (cb >> 1),
               (char*)Ks[bi] + (w * 128 + i * 64) * 16);
    }
  };
  auto stageV = [&](int t) {
    const int kv0 = t << 6;
#pragma unroll
    for (int i = 0; i < 2; ++i) {
      int c = w * 128 + i * 64 + lane;
      int rowv = c >> 3;
      int cbv = ((c & 7) << 4) ^ ((rowv & 7) << 4);
      gl_lds16(vp + (long long)rowv * S + kv0 + (cbv >> 1),
               (char*)Vs + (w * 128 + i * 64) * 16);
    }
  };

  stageK(0, 0);
  asm volatile("s_waitcnt vmcnt(0)" ::: "memory");
  __builtin_amdgcn_s_barrier();
  asm volatile("" ::: "memory");

  for (int t = 0; t < ntiles; ++t) {
    const int buf = t & 1;
    const int kv0 = t << 6;
    const bool active = (kv0 <= q0w + 31);
    stageV(t);                               // V(t): 2 loads
    if (t + 1 < ntiles) stageK(buf ^ 1, t + 1);  // K(t+1): 2 loads
    if (active) {
      // ---- QK^T from Ks[buf] (resident since prev tile end) ----
      f32x4 s[2][4] = {};
#pragma unroll
      for (int ks = 0; ks < 4; ++ks)
#pragma unroll
        for (int n = 0; n < 4; ++n) {
          int row = n * 16 + l16;
          int off = row * 256 + ((ks * 64 + lh * 16) ^ ((row & 7) << 4));
          bf16x8 kb = *(const bf16x8*)((const char*)Ks[buf] + off);
#pragma unroll
          for (int m = 0; m < 2; ++m) s[m][n] = mfma16(aq[m][ks], kb, s[m][n]);
        }
      // ---- causal mask ----
      if (kv0 + 63 > q0w) {
#pragma unroll
        for (int m = 0; m < 2; ++m)
#pragma unroll
          for (int n = 0; n < 4; ++n)
#pragma unroll
            for (int r = 0; r < 4; ++r) {
              int col = kv0 + n * 16 + l16;
              int rowg = q0w + m * 16 + lh * 4 + r;
              if (col > rowg) s[m][n][r] = -1e30f;
            }
      }
      // ---- online softmax with defer-max (THR=8, log2 domain) ----
      float lm[2][4];
      bool okl = true;
#pragma unroll
      for (int m = 0; m < 2; ++m)
#pragma unroll
        for (int r = 0; r < 4; ++r) {
          lm[m][r] = fmaxf(fmaxf(s[m][0][r], s[m][1][r]), fmaxf(s[m][2][r], s[m][3][r]));
          okl = okl && (lm[m][r] <= mrow[m][r] + 8.f);
        }
      if (!__all(okl)) {
#pragma unroll
        for (int st = 1; st < 16; st <<= 1)
#pragma unroll
          for (int m = 0; m < 2; ++m)
#pragma unroll
            for (int r = 0; r < 4; ++r) lm[m][r] = fmaxf(lm[m][r], __shfl_xor(lm[m][r], st));
#pragma unroll
        for (int m = 0; m < 2; ++m)
#pragma unroll
          for (int r = 0; r < 4; ++r) {
            float mn = fmaxf(mrow[m][r], lm[m][r]);
            float resc = exp2f(mrow[m][r] - mn);
            mrow[m][r] = mn;
            lrow[m][r] *= resc;
#pragma unroll
            for (int dt = 0; dt < 8; ++dt) acc[m][dt][r] *= resc;
          }
      }
      // ---- P = exp2(s - m), store swizzled, accumulate l ----
#pragma unroll
      for (int m = 0; m < 2; ++m)
#pragma unroll
        for (int n = 0; n < 4; ++n)
#pragma unroll
          for (int r = 0; r < 4; ++r) {
            float p = exp2f(s[m][n][r] - mrow[m][r]);
            s[m][n][r] = p;
            int row = m * 16 + lh * 4 + r;
            *(bf16*)((char*)Ps[w] + row * 128 +
                     ((n * 32 + l16 * 2) ^ ((row & 7) << 4))) = (bf16)p;
          }
#pragma unroll
      for (int m = 0; m < 2; ++m)
#pragma unroll
        for (int r = 0; r < 4; ++r)
          lrow[m][r] += s[m][0][r] + s[m][1][r] + s[m][2][r] + s[m][3][r];
    }
    // ---- V(t) ready barrier (own loads via vmcnt(2): K(t+1) may fly) ----
    asm volatile("s_waitcnt vmcnt(2)" ::: "memory");
    __builtin_amdgcn_s_barrier();
    asm volatile("" ::: "memory");
    if (active) {
      // ---- PV: acc += P V ----
      bf16x8 pa[2][2];
#pragma unroll
      for (int m = 0; m < 2; ++m)
#pragma unroll
        for (int kf = 0; kf < 2; ++kf) {
          int row = m * 16 + l16;
          pa[m][kf] = *(const bf16x8*)((const char*)Ps[w] + row * 128 +
                                       ((kf * 64 + lh * 16) ^ ((row & 7) << 4)));
        }
#pragma unroll
      for (int dt = 0; dt < 8; ++dt) {
        int d = dt * 16 + l16;
#pragma unroll
        for (int kf = 0; kf < 2; ++kf) {
          int off = d * 128 + ((kf * 64 + lh * 16) ^ ((d & 7) << 4));
          bf16x8 vb = *(const bf16x8*)((const char*)Vs + off);
#pragma unroll
          for (int m = 0; m < 2; ++m) acc[m][dt] = mfma16(pa[m][kf], vb, acc[m][dt]);
        }
      }
    }
    // ---- tile-end barrier: K(t+1) resident, Vs/Ps free for reuse ----
    asm volatile("s_waitcnt vmcnt(0)" ::: "memory");
    __builtin_amdgcn_s_barrier();
    asm volatile("" ::: "memory");
  }

#pragma unroll
  for (int st = 1; st < 16; st <<= 1)
#pragma unroll
    for (int m = 0; m < 2; ++m)
#pragma unroll
      for (int r = 0; r < 4; ++r) lrow[m][r] += __shfl_xor(lrow[m][r], st);
  float inv[2][4];
#pragma unroll
  for (int m = 0; m < 2; ++m)
#pragma unroll
    for (int r = 0; r < 4; ++r) inv[m][r] = 1.f / lrow[m][r];
#pragma unroll
  for (int m = 0; m < 2; ++m)
#pragma unroll
    for (int dt = 0; dt < 8; ++dt)
#pragma unroll
      for (int r = 0; r < 4; ++r) {
        int rowg = q0w + m * 16 + lh * 4 + r;
        long long row = (long long)b * S + rowg;
        int col = h * HD + dt * 16 + l16;
        float gv = (float)gate[row * ldg + col];
        outc[row * ldo + col] = (bf16)(acc[m][dt][r] * inv[m][r] * gv);
      }
}

extern "C" void kernel_launch(void* const* d_in, const int* in_sizes, int n_in,
                              void* d_out, int out_size, void* d_ws, size_t ws_size,
                              hipStream_t stream) {
  const float* x = (const float*)d_in[0];
  const float* cosT = (const float*)d_in[2];
  const float* sinT = (const float*)d_in[3];
  const float* wq = (const float*)d_in[4];
  const float* wk = (const float*)d_in[5];
  const float* wv = (const float*)d_in[6];
  const float* wg = (const float*)d_in[7];
  const float* wo = (const float*)d_in[8];
  const float* qs = (const float*)d_in[9];
  const float* ksc = (const float*)d_in[10];
  float* out = (float*)d_out;
  char* ws = (char*)d_ws;

  if (ws_size < 146800640) return;
  bf16* xb = (bf16*)(ws);
  bf16* wcat = (bf16*)(ws + 33554432);
  bf16* woT = (bf16*)(ws + 54525952);
  bf16* C1 = (bf16*)(ws + 62914560);
  bf16* qbuf = xb;
  bf16* kbuf = wcat;
  bf16* vtbuf = wcat + 4194304;
  bf16* gatep = C1 + 3072;
  bf16* ctxg = C1;

  dim3 tb(32, 8);
  k_f32_to_bf16<<<8192, 256, 0, stream>>>(x, xb, Bb * S * Dd / 8);
  k_transpose_bf16<float><<<dim3(64, 64, 1), tb, 0, stream>>>(
      wq, 0, 1, 0, 2048, wcat, 0, 2048, 2048, 2048);
  k_transpose_bf16<float><<<dim3(16, 64, 1), tb, 0, stream>>>(
      wk, 0, 1, 0, 512, wcat + 2048 * 2048, 0, 2048, 2048, 512);
  k_transpose_bf16<float><<<dim3(16, 64, 1), tb, 0, stream>>>(
      wv, 0, 1, 0, 512, wcat + 2560 * 2048, 0, 2048, 2048, 512);
  k_transpose_bf16<float><<<dim3(64, 64, 1), tb, 0, stream>>>(
      wg, 0, 1, 0, 2048, wcat + 3072 * 2048, 0, 2048, 2048, 2048);
  k_transpose_bf16<float><<<dim3(64, 64, 1), tb, 0, stream>>>(
      wo, 0, 1, 0, 2048, woT, 0, 2048, 2048, 2048);
  // fused QKVG GEMM: (8192x2048) @ (2048x5120) -> C1 bf16
  k_gemm256<bf16><<<32 * 20, 512, 0, stream>>>(xb, 2048, wcat, 2048, C1, 5120,
                                               8192, 5120, 2048);
  // RMSNorm + RoPE; L2E/sqrt(128) folded into q so attention uses exp2
  k_rms_rope<<<32768, 256, 0, stream>>>(C1, 5120, 16, qs, cosT, sinT, qbuf,
                                        0.12751879523209308f, 131072);
  k_rms_rope<<<8192, 256, 0, stream>>>(C1 + 2048, 5120, 4, ksc, cosT, sinT, kbuf,
                                       1.0f, 32768);
  // V -> V^T (B,G,128,S)
  k_transpose_bf16<bf16><<<dim3(4, 64, 16), tb, 0, stream>>>(
      C1 + 2560, (long long)2048 * 5120, 4, 128, 5120, vtbuf,
      (long long)128 * 2048, 2048, 2048, 128);
  // gate = sigmoid(xwg) in-place
  k_sigmoid<<<8192, 256, 0, stream>>>(gatep, 5120, 256, 2097152);
  // flash attention v3 + gate -> C1 cols 0:2048
  k_flash3<<<512, 512, 0, stream>>>(qbuf, kbuf, vtbuf, gatep, 5120, ctxg, 5120);
  // output GEMM: (8192x2048) @ (2048x2048) -> out fp32
  k_gemm256<float><<<32 * 8, 512, 0, stream>>>(ctxg, 5120, woT, 2048, out, 2048,
                                               8192, 2048, 2048);
}

// Round 6
// 441.166 us; speedup vs baseline: 1.6061x; 1.0856x over previous
//
#include <hip/hip_runtime.h>

typedef __bf16 bf16;
typedef __attribute__((ext_vector_type(8))) __bf16 bf16x8;
typedef __attribute__((ext_vector_type(4))) float f32x4;

constexpr int Bb = 4, S = 2048, Dd = 2048, H = 16, G = 4, HD = 128;
constexpr float L2E = 1.4426950408889634f;

__device__ inline f32x4 mfma16(bf16x8 a, bf16x8 b, f32x4 c) {
  return __builtin_amdgcn_mfma_f32_16x16x32_bf16(a, b, c, 0, 0, 0);
}

__device__ inline void gl_lds16(const void* g, void* l) {
  __builtin_amdgcn_global_load_lds(
      (const __attribute__((address_space(1))) void*)g,
      (__attribute__((address_space(3))) void*)l, 16, 0, 0);
}

// ---------------- fp32 -> bf16 elementwise (vectorized) ----------------
__global__ __launch_bounds__(256) void k_f32_to_bf16(
    const float* __restrict__ in, bf16* __restrict__ out, int n8) {
  int i = blockIdx.x * 256 + threadIdx.x;
  if (i >= n8) return;
  const float4* p = (const float4*)(in + (long long)i * 8);
  float4 a = p[0], b = p[1];
  bf16x8 v;
  v[0] = (bf16)a.x; v[1] = (bf16)a.y; v[2] = (bf16)a.z; v[3] = (bf16)a.w;
  v[4] = (bf16)b.x; v[5] = (bf16)b.y; v[6] = (bf16)b.z; v[7] = (bf16)b.w;
  *(bf16x8*)(out + (long long)i * 8) = v;
}

// ---------------- 5 weight transposes in ONE launch ----------------
// z selects weight; out[c][r] = (bf16) in[r][c]; R=2048 always, ldout=2048.
__global__ __launch_bounds__(256) void k_wtrans(
    const float* __restrict__ wq, const float* __restrict__ wk,
    const float* __restrict__ wv, const float* __restrict__ wg,
    const float* __restrict__ wo, bf16* __restrict__ wcat,
    bf16* __restrict__ woT) {
  __shared__ float tile[32][33];
  const int z = blockIdx.z;
  const float* src;
  bf16* dst;
  int C;
  switch (z) {
    case 0: src = wq; C = 2048; dst = wcat; break;
    case 1: src = wk; C = 512; dst = wcat + (long long)2048 * 2048; break;
    case 2: src = wv; C = 512; dst = wcat + (long long)2560 * 2048; break;
    case 3: src = wg; C = 2048; dst = wcat + (long long)3072 * 2048; break;
    default: src = wo; C = 2048; dst = woT; break;
  }
  int c0 = blockIdx.x * 32, r0 = blockIdx.y * 32;
  if (c0 >= C) return;
  int tx = threadIdx.x, ty = threadIdx.y;
#pragma unroll
  for (int i = 0; i < 4; ++i) {
    int r = r0 + ty + i * 8, c = c0 + tx;
    tile[ty + i * 8][tx] = (c < C) ? src[(long long)r * C + c] : 0.f;
  }
  __syncthreads();
#pragma unroll
  for (int i = 0; i < 4; ++i) {
    int c = c0 + ty + i * 8, r = r0 + tx;
    if (c < C) dst[(long long)c * 2048 + r] = (bf16)tile[tx][ty + i * 8];
  }
}

// ---------------- transpose + convert bf16 (V -> V^T) ----------------
template <typename InT>
__global__ __launch_bounds__(256) void k_transpose_bf16(
    const InT* __restrict__ in, long long s1, int nb2, long long s2, int ldin,
    bf16* __restrict__ out, long long obatch, int ldout, int R, int C) {
  __shared__ float tile[32][33];
  int z = blockIdx.z;
  const InT* ip = in + (long long)(z / nb2) * s1 + (long long)(z % nb2) * s2;
  bf16* op = out + (long long)z * obatch;
  int c0 = blockIdx.x * 32, r0 = blockIdx.y * 32;
  int tx = threadIdx.x, ty = threadIdx.y;
#pragma unroll
  for (int i = 0; i < 4; ++i) {
    int r = r0 + ty + i * 8, c = c0 + tx;
    tile[ty + i * 8][tx] = (r < R && c < C) ? (float)ip[(long long)r * ldin + c] : 0.f;
  }
  __syncthreads();
#pragma unroll
  for (int i = 0; i < 4; ++i) {
    int c = c0 + ty + i * 8, r = r0 + tx;
    if (c < C && r < R) op[(long long)c * ldout + r] = (bf16)tile[tx][ty + i * 8];
  }
}

// ---------------- 256x256 pipelined bf16 GEMM v2 ---------------------------
// C = A(MxK)*Bt(NxK)^T. 8 waves (2Mx4N), BK=64, dbuf 128KB LDS, XOR swizzle.
// 4 phases/K-tile; frag reads + stage issue inside MFMA shadow; vmcnt(4) at
// Q1/Q3/Q4 per explicit ledger; stages clamped (never skipped) so counts are
// exact at the K tail. launch_bounds(512,1): LDS caps 1 block/CU anyway.
template <typename CT, bool SIG>
__global__ __launch_bounds__(512, 1) void k_gemm256(
    const bf16* __restrict__ A, int lda, const bf16* __restrict__ Bt, int ldb,
    CT* __restrict__ C, int ldc, int M, int N, int K, int sig_from) {
  __shared__ bf16 ldsbuf[65536];  // 128 KB
  char* lds2 = (char*)ldsbuf;
  const int tid = threadIdx.x;
  const int w = tid >> 6, lane = tid & 63;
  const int l16 = lane & 15, lh = lane >> 4;
  const int wr = w >> 2, wc = w & 3;
  const int nbn = N >> 8;
  const int cpx = gridDim.x >> 3;
  const int swz = (blockIdx.x & 7) * cpx + (blockIdx.x >> 3);
  const int bm = swz / nbn, bn = swz % nbn;
  const int m0 = bm << 8, n0 = bn << 8;

  const int lrow = lane >> 3;
  const int lcol = ((lane & 7) ^ lrow) * 8;  // pre-swizzled source column
  const int arb = wr * 128 + wc * 16;
  const int xg = wc >> 1, sg = wr * 2 + (wc & 1);
  const int brb = xg * 128 + (sg >> 1) * 64 + (sg & 1) * 16;
  const bf16* aS0 = A + (long long)(m0 + arb + lrow) * lda + lcol;
  const bf16* aS1 = A + (long long)(m0 + arb + 8 + lrow) * lda + lcol;
  const bf16* bS0 = Bt + (long long)(n0 + brb + lrow) * ldb + lcol;
  const bf16* bS1 = Bt + (long long)(n0 + brb + 8 + lrow) * ldb + lcol;

  // one stage unit = 2 gl_lds; k clamped so units are NEVER skipped (ledger)
  auto stageA = [&](int buf, int k0, int hi) {
    k0 = (k0 < K) ? k0 : 0;
    gl_lds16(aS0 + (long long)hi * 64 * lda + k0,
             lds2 + buf * 65536 + (arb + hi * 64) * 128);
    gl_lds16(aS1 + (long long)hi * 64 * lda + k0,
             lds2 + buf * 65536 + (arb + hi * 64 + 8) * 128);
  };
  auto stageB = [&](int buf, int k0, int hi) {
    k0 = (k0 < K) ? k0 : 0;
    gl_lds16(bS0 + (long long)hi * 32 * ldb + k0,
             lds2 + buf * 65536 + 32768 + (brb + hi * 32) * 128);
    gl_lds16(bS1 + (long long)hi * 32 * ldb + k0,
             lds2 + buf * 65536 + 32768 + (brb + hi * 32 + 8) * 128);
  };

  const int swzc = (l16 & 7) << 4;
  auto rdA = [&](bf16x8 (&dst)[4][2], const char* L, int mh) {
#pragma unroll
    for (int m = 0; m < 4; ++m)
#pragma unroll
      for (int ks = 0; ks < 2; ++ks)
        dst[m][ks] = *(const bf16x8*)(L + (wr * 128 + mh * 64 + m * 16 + l16) * 128 +
                                      ((ks * 64 + lh * 16) ^ swzc));
  };
  auto rdB = [&](bf16x8 (&dst)[2][2], const char* L, int nh) {
#pragma unroll
    for (int n = 0; n < 2; ++n)
#pragma unroll
      for (int ks = 0; ks < 2; ++ks)
        dst[n][ks] = *(const bf16x8*)(L + 32768 + (wc * 64 + nh * 32 + n * 16 + l16) * 128 +
                                      ((ks * 64 + lh * 16) ^ swzc));
  };

  f32x4 acc[8][4] = {};
  bf16x8 aflo[4][2], afhi[4][2], bn0[2][2], bn1[2][2];
  const int NT = K >> 6;

  // prologue: SA0(0),SB0(0),SB1(0),SA1(0),SA0(1) = 10 loads
  stageA(0, 0, 0);
  stageB(0, 0, 0);
  stageB(0, 0, 1);
  stageA(0, 0, 1);
  stageA(1, 64, 0);
  asm volatile("s_waitcnt vmcnt(4)" ::: "memory");  // SA0(0),SB0(0),SB1(0) done
  __builtin_amdgcn_s_barrier();
  asm volatile("" ::: "memory");
  rdA(aflo, lds2, 0);
  rdB(bn0, lds2, 0);

  for (int t = 0; t < NT; ++t) {
    const int buf = t & 1, nb = buf ^ 1;
    const char* L = lds2 + buf * 65536;
    const char* Ln = lds2 + nb * 65536;
    const int k1 = (t + 1) << 6;
    const bool more = (t + 1 < NT);
    // ---- Q1: MFMA mlo x n01; prefetch bn1(cur); stage SB0(t+1) ----
    stageB(nb, k1, 0);
    rdB(bn1, L, 1);
    __builtin_amdgcn_s_setprio(1);
#pragma unroll
    for (int m = 0; m < 4; ++m)
#pragma unroll
      for (int n = 0; n < 2; ++n)
#pragma unroll
        for (int ks = 0; ks < 2; ++ks)
          acc[m][n] = mfma16(aflo[m][ks], bn0[n][ks], acc[m][n]);
    __builtin_amdgcn_s_setprio(0);
    asm volatile("s_waitcnt vmcnt(4)" ::: "memory");  // drains SA1(t)
    __builtin_amdgcn_s_barrier();
    asm volatile("" ::: "memory");
    // ---- Q2: MFMA mlo x n23; prefetch afhi(cur); stage SB1(t+1) ----
    stageB(nb, k1, 1);
    rdA(afhi, L, 1);
    __builtin_amdgcn_s_setprio(1);
#pragma unroll
    for (int m = 0; m < 4; ++m)
#pragma unroll
      for (int n = 0; n < 2; ++n)
#pragma unroll
        for (int ks = 0; ks < 2; ++ks)
          acc[m][2 + n] = mfma16(aflo[m][ks], bn1[n][ks], acc[m][2 + n]);
    __builtin_amdgcn_s_setprio(0);
    __builtin_amdgcn_s_barrier();
    asm volatile("" ::: "memory");
    // ---- Q3: MFMA mhi x n23; stage SA1(t+1) ----
    stageA(nb, k1, 1);
    __builtin_amdgcn_s_setprio(1);
#pragma unroll
    for (int m = 0; m < 4; ++m)
#pragma unroll
      for (int n = 0; n < 2; ++n)
#pragma unroll
        for (int ks = 0; ks < 2; ++ks)
          acc[4 + m][2 + n] = mfma16(afhi[m][ks], bn1[n][ks], acc[4 + m][2 + n]);
    __builtin_amdgcn_s_setprio(0);
    asm volatile("s_waitcnt vmcnt(4)" ::: "memory");  // drains SA0(t+1),SB0(t+1)
    __builtin_amdgcn_s_barrier();
    asm volatile("" ::: "memory");
    // ---- Q4: MFMA mhi x n01; prefetch aflo(next) early, bn0(next) late;
    //          stage SA0(t+2) into current buf ----
    if (more) rdA(aflo, Ln, 0);
    stageA(buf, (t + 2) << 6, 0);
    __builtin_amdgcn_s_setprio(1);
#pragma unroll
    for (int m = 0; m < 4; ++m)
#pragma unroll
      for (int n = 0; n < 2; ++n)
#pragma unroll
        for (int ks = 0; ks < 2; ++ks)
          acc[4 + m][n] = mfma16(afhi[m][ks], bn0[n][ks], acc[4 + m][n]);
    __builtin_amdgcn_s_setprio(0);
    if (more) rdB(bn0, Ln, 0);  // WAR on bn0 keeps this after the MFMAs
    asm volatile("s_waitcnt vmcnt(4)" ::: "memory");  // drains SB1(t+1)
    __builtin_amdgcn_s_barrier();
    asm volatile("" ::: "memory");
  }

#pragma unroll
  for (int m = 0; m < 8; ++m)
#pragma unroll
    for (int n = 0; n < 4; ++n) {
      const int col = n0 + wc * 64 + n * 16 + l16;
#pragma unroll
      for (int r = 0; r < 4; ++r) {
        float v = acc[m][n][r];
        if (SIG && col >= sig_from) v = 1.f / (1.f + exp2f(-v * L2E));
        C[(long long)(m0 + wr * 128 + m * 16 + lh * 4 + r) * ldc + col] = (CT)v;
      }
    }
}

// ---------------- RMSNorm + RoPE, Q and K in one launch ----------------
__global__ __launch_bounds__(256) void k_rms_rope2(
    const bf16* __restrict__ C1, const float* __restrict__ qs,
    const float* __restrict__ ksc, const float* __restrict__ cosT,
    const float* __restrict__ sinT, bf16* __restrict__ qb,
    bf16* __restrict__ kb) {
  int wid = (blockIdx.x * 256 + threadIdx.x) >> 6;
  int lane = threadIdx.x & 63;
  const bf16* ip;
  const float* scale;
  bf16* op;
  float oscale;
  int s;
  if (wid < 131072) {  // Q: nh=16, scaled by L2E/sqrt(HD)
    int h = wid & 15, bs = wid >> 4;
    s = bs & 2047;
    int b = bs >> 11;
    ip = C1 + (long long)bs * 5120 + h * HD;
    scale = qs;
    oscale = 0.12751879523209308f;
    op = qb + (((long long)b * H + h) * S + s) * HD;
  } else {  // K: nh=4
    wid -= 131072;
    int h = wid & 3, bs = wid >> 2;
    s = bs & 2047;
    int b = bs >> 11;
    ip = C1 + 2048 + (long long)bs * 5120 + h * HD;
    scale = ksc;
    oscale = 1.0f;
    op = kb + (((long long)b * G + h) * S + s) * HD;
  }
  float x1 = (float)ip[lane], x2 = (float)ip[lane + 64];
  float ss = x1 * x1 + x2 * x2;
#pragma unroll
  for (int m = 1; m < 64; m <<= 1) ss += __shfl_xor(ss, m);
  float rms = rsqrtf(ss * (1.f / 128.f) + 1e-6f);
  float n1 = x1 * rms * (1.f + scale[lane]);
  float n2 = x2 * rms * (1.f + scale[lane + 64]);
  float o1 = (n1 * cosT[s * 128 + lane] - n2 * sinT[s * 128 + lane]) * oscale;
  float o2 = (n2 * cosT[s * 128 + lane + 64] + n1 * sinT[s * 128 + lane + 64]) * oscale;
  op[lane] = (bf16)o1;
  op[lane + 64] = (bf16)o2;
}

// ---------------- causal GQA flash attention v3 (R5 known-good) ----------
__global__ __launch_bounds__(512, 2) void k_flash3(
    const bf16* __restrict__ Q, const bf16* __restrict__ Kb,
    const bf16* __restrict__ Vt, const bf16* __restrict__ gate, int ldg,
    bf16* __restrict__ outc, int ldo) {
  __shared__ bf16 Ks[2][64 * 128];
  __shared__ bf16 Vs[128 * 64];
  __shared__ bf16 Ps[8][32 * 64];
  const int tid = threadIdx.x, w = tid >> 6, lane = tid & 63;
  const int l16 = lane & 15, lh = lane >> 4;
  const int bh = blockIdx.x & 63;
  const int qi = blockIdx.x >> 6;
  const int qc = 7 - qi;
  const int h = bh & 15, b = bh >> 4, g = h >> 2;
  const int qbase = qc * 256;
  const int q0w = qbase + w * 32;
  const bf16* qp = Q + (((long long)b * H + h) * S + q0w) * HD;
  const bf16* kp = Kb + ((long long)b * G + g) * S * HD;
  const bf16* vp = Vt + ((long long)b * G + g) * (long long)HD * S;

  bf16x8 aq[2][4];
#pragma unroll
  for (int m = 0; m < 2; ++m)
#pragma unroll
    for (int ks = 0; ks < 4; ++ks)
      aq[m][ks] = *(const bf16x8*)(qp + (long long)(m * 16 + l16) * HD + ks * 32 + lh * 8);

  f32x4 acc[2][8] = {};
  float mrow[2][4], lrow[2][4];
#pragma unroll
  for (int m = 0; m < 2; ++m)
#pragma unroll
    for (int r = 0; r < 4; ++r) { mrow[m][r] = -1e30f; lrow[m][r] = 0.f; }

  const int ntiles = qc * 4 + 4;

  auto stageK = [&](int bi, int t) {
    const int kv0 = t << 6;
#pragma unroll
    for (int i = 0; i < 2; ++i) {
      int c = w * 128 + i * 64 + lane;
      int row = c >> 4;
      int cb = ((c & 15) << 4) ^ ((row & 7) << 4);
      gl_lds16(kp + (long long)(kv0 + row) * HD + (cb >> 1),
               (char*)Ks[bi] + (w * 128 + i * 64) * 16);
    }
  };
  auto stageV = [&](int t) {
    const int kv0 = t << 6;
#pragma unroll
    for (int i = 0; i < 2; ++i) {
      int c = w * 128 + i * 64 + lane;
      int rowv = c >> 3;
      int cbv = ((c & 7) << 4) ^ ((rowv & 7) << 4);
      gl_lds16(vp + (long long)rowv * S + kv0 + (cbv >> 1),
               (char*)Vs + (w * 128 + i * 64) * 16);
    }
  };

  stageK(0, 0);
  asm volatile("s_waitcnt vmcnt(0)" ::: "memory");
  __builtin_amdgcn_s_barrier();
  asm volatile("" ::: "memory");

  for (int t = 0; t < ntiles; ++t) {
    const int buf = t & 1;
    const int kv0 = t << 6;
    const bool active = (kv0 <= q0w + 31);
    stageV(t);
    if (t + 1 < ntiles) stageK(buf ^ 1, t + 1);
    if (active) {
      f32x4 s[2][4] = {};
#pragma unroll
      for (int ks = 0; ks < 4; ++ks)
#pragma unroll
        for (int n = 0; n < 4; ++n) {
          int row = n * 16 + l16;
          int off = row * 256 + ((ks * 64 + lh * 16) ^ ((row & 7) << 4));
          bf16x8 kb = *(const bf16x8*)((const char*)Ks[buf] + off);
#pragma unroll
          for (int m = 0; m < 2; ++m) s[m][n] = mfma16(aq[m][ks], kb, s[m][n]);
        }
      if (kv0 + 63 > q0w) {
#pragma unroll
        for (int m = 0; m < 2; ++m)
#pragma unroll
          for (int n = 0; n < 4; ++n)
#pragma unroll
            for (int r = 0; r < 4; ++r) {
              int col = kv0 + n * 16 + l16;
              int rowg = q0w + m * 16 + lh * 4 + r;
              if (col > rowg) s[m][n][r] = -1e30f;
            }
      }
      float lm[2][4];
      bool okl = true;
#pragma unroll
      for (int m = 0; m < 2; ++m)
#pragma unroll
        for (int r = 0; r < 4; ++r) {
          lm[m][r] = fmaxf(fmaxf(s[m][0][r], s[m][1][r]), fmaxf(s[m][2][r], s[m][3][r]));
          okl = okl && (lm[m][r] <= mrow[m][r] + 8.f);
        }
      if (!__all(okl)) {
#pragma unroll
        for (int st = 1; st < 16; st <<= 1)
#pragma unroll
          for (int m = 0; m < 2; ++m)
#pragma unroll
            for (int r = 0; r < 4; ++r) lm[m][r] = fmaxf(lm[m][r], __shfl_xor(lm[m][r], st));
#pragma unroll
        for (int m = 0; m < 2; ++m)
#pragma unroll
          for (int r = 0; r < 4; ++r) {
            float mn = fmaxf(mrow[m][r], lm[m][r]);
            float resc = exp2f(mrow[m][r] - mn);
            mrow[m][r] = mn;
            lrow[m][r] *= resc;
#pragma unroll
            for (int dt = 0; dt < 8; ++dt) acc[m][dt][r] *= resc;
          }
      }
#pragma unroll
      for (int m = 0; m < 2; ++m)
#pragma unroll
        for (int n = 0; n < 4; ++n)
#pragma unroll
          for (int r = 0; r < 4; ++r) {
            float p = exp2f(s[m][n][r] - mrow[m][r]);
            s[m][n][r] = p;
            int row = m * 16 + lh * 4 + r;
            *(bf16*)((char*)Ps[w] + row * 128 +
                     ((n * 32 + l16 * 2) ^ ((row & 7) << 4))) = (bf16)p;
          }
#pragma unroll
      for (int m = 0; m < 2; ++m)
#pragma unroll
        for (int r = 0; r < 4; ++r)
          lrow[m][r] += s[m][0][r] + s[m][1][r] + s[m][2][r] + s[m][3][r];
    }
    asm volatile("s_waitcnt vmcnt(2)" ::: "memory");
    __builtin_amdgcn_s_barrier();
    asm volatile("" ::: "memory");
    if (active) {
      bf16x8 pa[2][2];
#pragma unroll
      for (int m = 0; m < 2; ++m)
#pragma unroll
        for (int kf = 0; kf < 2; ++kf) {
          int row = m * 16 + l16;
          pa[m][kf] = *(const bf16x8*)((const char*)Ps[w] + row * 128 +
                                       ((kf * 64 + lh * 16) ^ ((row & 7) << 4)));
        }
#pragma unroll
      for (int dt = 0; dt < 8; ++dt) {
        int d = dt * 16 + l16;
#pragma unroll
        for (int kf = 0; kf < 2; ++kf) {
          int off = d * 128 + ((kf * 64 + lh * 16) ^ ((d & 7) << 4));
          bf16x8 vb = *(const bf16x8*)((const char*)Vs + off);
#pragma unroll
          for (int m = 0; m < 2; ++m) acc[m][dt] = mfma16(pa[m][kf], vb, acc[m][dt]);
        }
      }
    }
    asm volatile("s_waitcnt vmcnt(0)" ::: "memory");
    __builtin_amdgcn_s_barrier();
    asm volatile("" ::: "memory");
  }

#pragma unroll
  for (int st = 1; st < 16; st <<= 1)
#pragma unroll
    for (int m = 0; m < 2; ++m)
#pragma unroll
      for (int r = 0; r < 4; ++r) lrow[m][r] += __shfl_xor(lrow[m][r], st);
  float inv[2][4];
#pragma unroll
  for (int m = 0; m < 2; ++m)
#pragma unroll
    for (int r = 0; r < 4; ++r) inv[m][r] = 1.f / lrow[m][r];
#pragma unroll
  for (int m = 0; m < 2; ++m)
#pragma unroll
    for (int dt = 0; dt < 8; ++dt)
#pragma unroll
      for (int r = 0; r < 4; ++r) {
        int rowg = q0w + m * 16 + lh * 4 + r;
        long long row = (long long)b * S + rowg;
        int col = h * HD + dt * 16 + l16;
        float gv = (float)gate[row * ldg + col];
        outc[row * ldo + col] = (bf16)(acc[m][dt][r] * inv[m][r] * gv);
      }
}

extern "C" void kernel_launch(void* const* d_in, const int* in_sizes, int n_in,
                              void* d_out, int out_size, void* d_ws, size_t ws_size,
                              hipStream_t stream) {
  const float* x = (const float*)d_in[0];
  const float* cosT = (const float*)d_in[2];
  const float* sinT = (const float*)d_in[3];
  const float* wq = (const float*)d_in[4];
  const float* wk = (const float*)d_in[5];
  const float* wv = (const float*)d_in[6];
  const float* wg = (const float*)d_in[7];
  const float* wo = (const float*)d_in[8];
  const float* qs = (const float*)d_in[9];
  const float* ksc = (const float*)d_in[10];
  float* out = (float*)d_out;
  char* ws = (char*)d_ws;

  if (ws_size < 146800640) return;
  bf16* xb = (bf16*)(ws);
  bf16* wcat = (bf16*)(ws + 33554432);
  bf16* woT = (bf16*)(ws + 54525952);
  bf16* C1 = (bf16*)(ws + 62914560);
  bf16* qbuf = xb;
  bf16* kbuf = wcat;
  bf16* vtbuf = wcat + 4194304;
  bf16* gatep = C1 + 3072;
  bf16* ctxg = C1;

  dim3 tb(32, 8);
  // 1. x -> bf16
  k_f32_to_bf16<<<8192, 256, 0, stream>>>(x, xb, Bb * S * Dd / 8);
  // 2. all 5 weight transposes, one launch
  k_wtrans<<<dim3(64, 64, 5), tb, 0, stream>>>(wq, wk, wv, wg, wo, wcat, woT);
  // 3. fused QKVG GEMM + sigmoid on gate cols (>=3072)
  k_gemm256<bf16, true><<<32 * 20, 512, 0, stream>>>(
      xb, 2048, wcat, 2048, C1, 5120, 8192, 5120, 2048, 3072);
  // 4. RMSNorm + RoPE for Q and K, one launch
  k_rms_rope2<<<40960, 256, 0, stream>>>(C1, qs, ksc, cosT, sinT, qbuf, kbuf);
  // 5. V -> V^T (B,G,128,S)
  k_transpose_bf16<bf16><<<dim3(4, 64, 16), tb, 0, stream>>>(
      C1 + 2560, (long long)2048 * 5120, 4, 128, 5120, vtbuf,
      (long long)128 * 2048, 2048, 2048, 128);
  // 6. flash attention + gate -> C1 cols 0:2048
  k_flash3<<<512, 512, 0, stream>>>(qbuf, kbuf, vtbuf, gatep, 5120, ctxg, 5120);
  // 7. output GEMM -> out fp32
  k_gemm256<float, false><<<32 * 8, 512, 0, stream>>>(
      ctxg, 5120, woT, 2048, out, 2048, 8192, 2048, 2048, 1 << 30);
}